// Round 12
// baseline (253.781 us; speedup 1.0000x reference)
//
#include <hip/hip_runtime.h>
#include <hip/hip_bf16.h>
#include <math.h>

#define NN 50000
#define NE 800000
#define ET (NE + NN)
#define FIN 128
#define HEADS 8
#define HID 32
#define C1 (HEADS * HID)   // 256
#define NG 64
#define NEG 0.2f

#define EPB 4096           // edges per block in bucket scatter
#define NBKT 782           // ceil(NN/64)
#define CAP 2048           // slots per bucket (expected ~1087)
#define CAPP 768           // slots per quarter-bucket (expected ~272)

typedef __attribute__((ext_vector_type(8))) unsigned short ushort8_t;
typedef __attribute__((ext_vector_type(4))) unsigned short ushort4_t;
typedef __attribute__((ext_vector_type(2))) float float2_t;
typedef __attribute__((ext_vector_type(8))) short bf16x8;
typedef __attribute__((ext_vector_type(4))) float f32x4;

__device__ __forceinline__ float lrelu(float v) { return v > 0.f ? v : NEG * v; }
__device__ __forceinline__ float elu1(float v)  { return v > 0.f ? v : expm1f(v); }
__device__ __forceinline__ unsigned short f2bf(float f) {
    __hip_bfloat16 b = __float2bfloat16(f);
    return *reinterpret_cast<unsigned short*>(&b);
}
__device__ __forceinline__ float bf2f(unsigned short u) {
    return __uint_as_float(((unsigned)u) << 16);
}
// decode 16 fp8 (uint4), accumulate e*val into 8 float2 accumulators (v_pk_fma_f32)
__device__ __forceinline__ void dec_fma16(uint4 r, float e, float2_t* acc) {
    float2_t ev = {e, e};
    acc[0] += ev * __builtin_amdgcn_cvt_pk_f32_fp8((int)r.x, false);
    acc[1] += ev * __builtin_amdgcn_cvt_pk_f32_fp8((int)r.x, true);
    acc[2] += ev * __builtin_amdgcn_cvt_pk_f32_fp8((int)r.y, false);
    acc[3] += ev * __builtin_amdgcn_cvt_pk_f32_fp8((int)r.y, true);
    acc[4] += ev * __builtin_amdgcn_cvt_pk_f32_fp8((int)r.z, false);
    acc[5] += ev * __builtin_amdgcn_cvt_pk_f32_fp8((int)r.z, true);
    acc[6] += ev * __builtin_amdgcn_cvt_pk_f32_fp8((int)r.w, false);
    acc[7] += ev * __builtin_amdgcn_cvt_pk_f32_fp8((int)r.w, true);
}

// ---------------- bucket scatter (standalone: 19.5 KB LDS, full occupancy) ----------------
// packed edge: s(16 bits) | (d&63)<<16 | (d>>6)<<22  — NN<65536, NBKT<1024
__global__ __launch_bounds__(256) void bkt_scatter_kernel(const int* __restrict__ ei,
                                                          int* __restrict__ bcur,
                                                          unsigned* __restrict__ bkt) {
    __shared__ unsigned ep[EPB];   // 16 KB
    __shared__ int lh[NBKT];       // 3.1 KB
    int t = threadIdx.x;
    int base = blockIdx.x * EPB;
    int nloc = ET - base; if (nloc > EPB) nloc = EPB;
    for (int i = t; i < NBKT; i += 256) lh[i] = 0;
    __syncthreads();
    for (int k = t; k < nloc; k += 256) {
        int i = base + k;
        int s, d;
        if (i < NE) { s = ei[i]; d = ei[NE + i]; }
        else        { s = i - NE; d = s; }
        ep[k] = (unsigned)s | ((unsigned)(d & 63) << 16) | ((unsigned)(d >> 6) << 22);
        atomicAdd(&lh[d >> 6], 1);
    }
    __syncthreads();
    for (int i = t; i < NBKT; i += 256) {
        int c = lh[i];
        lh[i] = c ? atomicAdd(&bcur[i], c) : 0;
    }
    __syncthreads();
    for (int k = t; k < nloc; k += 256) {
        unsigned v = ep[k];
        int b = (int)(v >> 22);
        int pos = atomicAdd(&lh[b], 1);
        if (pos < CAP) bkt[(size_t)b * CAP + pos] = v & 0x3FFFFFu;  // s | dl<<16
    }
}

// ---------------- W1+W2 fp32 -> bf16 swizzled B-fragments (merged) ----------------
__global__ __launch_bounds__(256) void cvt_w_kernel(const float* __restrict__ W1,
                                                    const float* __restrict__ W2,
                                                    unsigned short* __restrict__ w1swz,
                                                    unsigned short* __restrict__ w2swz) {
    int bid = blockIdx.x;
    if (bid < 16) {
        int t = bid * 256 + threadIdx.x;
        int fid = t >> 6, lane = t & 63;
        int tnt = fid >> 2, ks = fid & 3;
        int n = tnt * 16 + (lane & 15);
        int k0 = ks * 32 + (lane >> 4) * 8;
        ushort8_t o;
        #pragma unroll
        for (int j = 0; j < 8; ++j) o[j] = f2bf(W1[(k0 + j) * C1 + n]);
        *(ushort8_t*)&w1swz[(size_t)(fid * 64 + lane) * 8] = o;
    } else {
        int t = (bid - 16) * 256 + threadIdx.x;
        int fid = t >> 6, lane = t & 63;
        int nt = fid >> 3, ks = fid & 7;
        int n = nt * 16 + (lane & 15);
        int k0 = ks * 32 + (lane >> 4) * 8;
        ushort8_t o;
        #pragma unroll
        for (int j = 0; j < 8; ++j) o[j] = f2bf(W2[(k0 + j) * HID + n]);
        *(ushort8_t*)&w2swz[(size_t)(fid * 64 + lane) * 8] = o;
    }
}

// ---------------- GEMM1 (MFMA bf16, f32 x in): h1 = x @ W1 (fp8 out), fused att1 ----------------
__global__ __launch_bounds__(256) void gemm1_kernel(
        const float* __restrict__ x, const unsigned short* __restrict__ w1swz,
        const float* __restrict__ attS, const float* __restrict__ attD,
        unsigned char* __restrict__ h1f8, float* __restrict__ aS, float* __restrict__ aD) {
    __shared__ float lds[4 * 16 * 132];
    int t = threadIdx.x, w = t >> 6, lane = t & 63;
    int mh = w & 1, nh = w >> 1;
    int m0 = blockIdx.x * 64 + mh * 32;
    int l15 = lane & 15, l4 = lane >> 4;

    f32x4 acc[2][8];
    #pragma unroll
    for (int mt = 0; mt < 2; ++mt)
        #pragma unroll
        for (int nt = 0; nt < 8; ++nt)
            acc[mt][nt] = (f32x4){0.f, 0.f, 0.f, 0.f};

    int ra = m0 + l15;       if (ra >= NN) ra = NN - 1;
    int rb = m0 + 16 + l15;  if (rb >= NN) rb = NN - 1;
    const float* a0p = x + (size_t)ra * FIN + l4 * 8;
    const float* a1p = x + (size_t)rb * FIN + l4 * 8;

    #pragma unroll
    for (int ks = 0; ks < 4; ++ks) {
        float4 f00 = *(const float4*)(a0p + ks * 32);
        float4 f01 = *(const float4*)(a0p + ks * 32 + 4);
        float4 f10 = *(const float4*)(a1p + ks * 32);
        float4 f11 = *(const float4*)(a1p + ks * 32 + 4);
        bf16x8 af0, af1;
        af0[0] = (short)f2bf(f00.x); af0[1] = (short)f2bf(f00.y);
        af0[2] = (short)f2bf(f00.z); af0[3] = (short)f2bf(f00.w);
        af0[4] = (short)f2bf(f01.x); af0[5] = (short)f2bf(f01.y);
        af0[6] = (short)f2bf(f01.z); af0[7] = (short)f2bf(f01.w);
        af1[0] = (short)f2bf(f10.x); af1[1] = (short)f2bf(f10.y);
        af1[2] = (short)f2bf(f10.z); af1[3] = (short)f2bf(f10.w);
        af1[4] = (short)f2bf(f11.x); af1[5] = (short)f2bf(f11.y);
        af1[6] = (short)f2bf(f11.z); af1[7] = (short)f2bf(f11.w);
        #pragma unroll
        for (int nt = 0; nt < 8; ++nt) {
            bf16x8 bf = *(const bf16x8*)&w1swz[(size_t)(((nh * 8 + nt) * 4 + ks) * 64 + lane) * 8];
            acc[0][nt] = __builtin_amdgcn_mfma_f32_16x16x32_bf16(af0, bf, acc[0][nt], 0, 0, 0);
            acc[1][nt] = __builtin_amdgcn_mfma_f32_16x16x32_bf16(af1, bf, acc[1][nt], 0, 0, 0);
        }
    }

    float* wl = lds + w * 16 * 132;
    #pragma unroll
    for (int mt = 0; mt < 2; ++mt) {
        __syncthreads();
        #pragma unroll
        for (int nt = 0; nt < 8; ++nt)
            #pragma unroll
            for (int r = 0; r < 4; ++r)
                wl[(l4 * 4 + r) * 132 + nt * 16 + l15] = acc[mt][nt][r];
        __syncthreads();
        int row_g = m0 + mt * 16 + l15;
        int cch = l4;
        float v[32];
        #pragma unroll
        for (int i = 0; i < 8; ++i) {
            float4 f = *(const float4*)&wl[l15 * 132 + cch * 32 + i * 4];
            v[i * 4 + 0] = f.x; v[i * 4 + 1] = f.y; v[i * 4 + 2] = f.z; v[i * 4 + 3] = f.w;
        }
        if (row_g < NN) {
            unsigned pk[8];
            #pragma unroll
            for (int i = 0; i < 8; ++i) {
                int p = __builtin_amdgcn_cvt_pk_fp8_f32(v[i * 4 + 0], v[i * 4 + 1], 0, false);
                p = __builtin_amdgcn_cvt_pk_fp8_f32(v[i * 4 + 2], v[i * 4 + 3], p, true);
                pk[i] = (unsigned)p;
            }
            size_t base = (size_t)row_g * C1 + nh * 128 + cch * 32;
            *(uint4*)&h1f8[base]      = make_uint4(pk[0], pk[1], pk[2], pk[3]);
            *(uint4*)&h1f8[base + 16] = make_uint4(pk[4], pk[5], pk[6], pk[7]);
            int h = nh * 4 + cch;
            float ps = 0.f, pd = 0.f;
            #pragma unroll
            for (int i = 0; i < 32; ++i) {
                ps += v[i] * attS[h * 32 + i];
                pd += v[i] * attD[h * 32 + i];
            }
            aS[row_g * HEADS + h] = ps;
            aD[row_g * HEADS + h] = pd;
        }
    }
}

// ---------------- Layer-1 aggregation: quarter-bucket per block, LDS sort, no CSR ----------------
// block = bucket*4 + part; handles 16 nodes. Wave w: 4 nodes sequential, quarter-wave per edge.
__global__ __launch_bounds__(256) void agg1_kernel(
        const unsigned* __restrict__ bkt, const int* __restrict__ bcur,
        const float* __restrict__ aS, const float* __restrict__ aD,
        const unsigned char* __restrict__ h1f8, const float* __restrict__ b1,
        unsigned short* __restrict__ z1b) {
    __shared__ unsigned short srt[CAPP];
    __shared__ int cnt_s[16], base_s[16], cur_s[16];
    int bid = blockIdx.x;
    int b = bid >> 2, part = bid & 3;
    int t = threadIdx.x;
    int cnt = bcur[b]; if (cnt > CAP) cnt = CAP;
    if (t < 16) cnt_s[t] = 0;
    __syncthreads();
    const unsigned* e = bkt + (size_t)b * CAP;
    int dlo = part * 16;
    for (int k = t; k < cnt; k += 256) {
        int dl = (int)(e[k] >> 16) - dlo;
        if ((unsigned)dl < 16u) atomicAdd(&cnt_s[dl], 1);
    }
    __syncthreads();
    if (t < 16) {
        int v = cnt_s[t];
        int inc = v;
        #pragma unroll
        for (int off = 1; off < 16; off <<= 1) {
            int u = __shfl_up(inc, off, 64);
            if (t >= off) inc += u;
        }
        base_s[t] = inc - v;
        cur_s[t] = inc - v;
    }
    __syncthreads();
    for (int k = t; k < cnt; k += 256) {
        unsigned v = e[k];
        int dl = (int)(v >> 16) - dlo;
        if ((unsigned)dl < 16u) {
            int pos = atomicAdd(&cur_s[dl], 1);
            if (pos < CAPP) srt[pos] = (unsigned short)(v & 0xFFFFu);
        }
    }
    __syncthreads();
    int wv = t >> 6, lane = t & 63;
    int q = lane >> 4, sl = lane & 15;
    int h = sl >> 1;
    #pragma unroll
    for (int i = 0; i < 4; ++i) {
        int dl = wv * 4 + i;
        int d = b * 64 + dlo + dl;
        if (d >= NN) continue;               // wave-uniform
        int start = base_s[dl], end = start + cnt_s[dl];
        float adh = aD[d * HEADS + h];
        float2_t acc[8];
        #pragma unroll
        for (int i2 = 0; i2 < 8; ++i2) acc[i2] = (float2_t){0.f, 0.f};
        float den = 0.f;
        int j = start + q;
        for (; j + 4 < end; j += 8) {
            int s0 = srt[j], s1 = srt[j + 4];
            uint4 r0 = *(const uint4*)&h1f8[(size_t)s0 * C1 + sl * 16];
            uint4 r1 = *(const uint4*)&h1f8[(size_t)s1 * C1 + sl * 16];
            float e0 = __expf(lrelu(aS[s0 * HEADS + h] + adh));
            float e1 = __expf(lrelu(aS[s1 * HEADS + h] + adh));
            den += e0 + e1;
            dec_fma16(r0, e0, acc);
            dec_fma16(r1, e1, acc);
        }
        for (; j < end; j += 4) {
            int s = srt[j];
            uint4 r = *(const uint4*)&h1f8[(size_t)s * C1 + sl * 16];
            float ee = __expf(lrelu(aS[s * HEADS + h] + adh));
            den += ee;
            dec_fma16(r, ee, acc);
        }
        den += __shfl_xor(den, 16, 64);
        den += __shfl_xor(den, 32, 64);
        #pragma unroll
        for (int i2 = 0; i2 < 8; ++i2) {
            acc[i2].x += __shfl_xor(acc[i2].x, 16, 64);
            acc[i2].y += __shfl_xor(acc[i2].y, 16, 64);
            acc[i2].x += __shfl_xor(acc[i2].x, 32, 64);
            acc[i2].y += __shfl_xor(acc[i2].y, 32, 64);
        }
        float invd = 1.f / (den + 1e-16f);
        int cb = sl * 16 + q * 4;
        float4 bb = *(const float4*)&b1[cb];
        ushort4_t o;
        o[0] = f2bf(elu1(acc[q * 2 + 0].x * invd + bb.x));
        o[1] = f2bf(elu1(acc[q * 2 + 0].y * invd + bb.y));
        o[2] = f2bf(elu1(acc[q * 2 + 1].x * invd + bb.z));
        o[3] = f2bf(elu1(acc[q * 2 + 1].y * invd + bb.w));
        *(ushort4_t*)&z1b[(size_t)d * C1 + cb] = o;
    }
}

// ---------------- GEMM2 (MFMA bf16): h2 = z1 @ W2 (bf16 out), fused att2 ----------------
__global__ __launch_bounds__(256) void gemm2_kernel(
        const unsigned short* __restrict__ z1b, const unsigned short* __restrict__ w2swz,
        const float* __restrict__ attS, const float* __restrict__ attD,
        unsigned short* __restrict__ h2b, float* __restrict__ aS2, float* __restrict__ aD2) {
    __shared__ float lds[4 * 16 * 36];
    int t = threadIdx.x, w = t >> 6, lane = t & 63;
    int m0 = blockIdx.x * 64 + w * 16;
    int l15 = lane & 15, l4 = lane >> 4;

    f32x4 acc[2];
    acc[0] = (f32x4){0.f, 0.f, 0.f, 0.f};
    acc[1] = (f32x4){0.f, 0.f, 0.f, 0.f};

    int ra = m0 + l15; if (ra >= NN) ra = NN - 1;
    const unsigned short* ap = z1b + (size_t)ra * C1 + l4 * 8;

    #pragma unroll
    for (int ks = 0; ks < 8; ++ks) {
        bf16x8 af = *(const bf16x8*)(ap + ks * 32);
        #pragma unroll
        for (int nt = 0; nt < 2; ++nt) {
            bf16x8 bf = *(const bf16x8*)&w2swz[(size_t)((nt * 8 + ks) * 64 + lane) * 8];
            acc[nt] = __builtin_amdgcn_mfma_f32_16x16x32_bf16(af, bf, acc[nt], 0, 0, 0);
        }
    }
    float* wl = lds + w * 16 * 36;
    #pragma unroll
    for (int nt = 0; nt < 2; ++nt)
        #pragma unroll
        for (int r = 0; r < 4; ++r)
            wl[(l4 * 4 + r) * 36 + nt * 16 + l15] = acc[nt][r];
    __syncthreads();
    int row_g = m0 + l15;
    float v[8];
    {
        float4 f0 = *(const float4*)&wl[l15 * 36 + l4 * 8];
        float4 f1 = *(const float4*)&wl[l15 * 36 + l4 * 8 + 4];
        v[0] = f0.x; v[1] = f0.y; v[2] = f0.z; v[3] = f0.w;
        v[4] = f1.x; v[5] = f1.y; v[6] = f1.z; v[7] = f1.w;
    }
    float ps = 0.f, pd = 0.f;
    #pragma unroll
    for (int i = 0; i < 8; ++i) {
        ps += v[i] * attS[l4 * 8 + i];
        pd += v[i] * attD[l4 * 8 + i];
    }
    ps += __shfl_xor(ps, 16, 64); ps += __shfl_xor(ps, 32, 64);
    pd += __shfl_xor(pd, 16, 64); pd += __shfl_xor(pd, 32, 64);
    if (row_g < NN) {
        ushort8_t o;
        #pragma unroll
        for (int i = 0; i < 8; ++i) o[i] = f2bf(v[i]);
        *(ushort8_t*)&h2b[(size_t)row_g * HID + l4 * 8] = o;
        if (l4 == 0) { aS2[row_g] = ps; aD2[row_g] = pd; }
    }
}

// ---------------- Layer-2 aggregation: quarter-bucket per block, LDS sort, no CSR ----------------
__global__ __launch_bounds__(256) void agg2_kernel(
        const unsigned* __restrict__ bkt, const int* __restrict__ bcur,
        const float* __restrict__ aS, const float* __restrict__ aD,
        const unsigned short* __restrict__ h2b, const float* __restrict__ b2,
        float* __restrict__ z2) {
    __shared__ unsigned short srt[CAPP];
    __shared__ int cnt_s[16], base_s[16], cur_s[16];
    int bid = blockIdx.x;
    int b = bid >> 2, part = bid & 3;
    int t = threadIdx.x;
    int cnt = bcur[b]; if (cnt > CAP) cnt = CAP;
    if (t < 16) cnt_s[t] = 0;
    __syncthreads();
    const unsigned* e = bkt + (size_t)b * CAP;
    int dlo = part * 16;
    for (int k = t; k < cnt; k += 256) {
        int dl = (int)(e[k] >> 16) - dlo;
        if ((unsigned)dl < 16u) atomicAdd(&cnt_s[dl], 1);
    }
    __syncthreads();
    if (t < 16) {
        int v = cnt_s[t];
        int inc = v;
        #pragma unroll
        for (int off = 1; off < 16; off <<= 1) {
            int u = __shfl_up(inc, off, 64);
            if (t >= off) inc += u;
        }
        base_s[t] = inc - v;
        cur_s[t] = inc - v;
    }
    __syncthreads();
    for (int k = t; k < cnt; k += 256) {
        unsigned v = e[k];
        int dl = (int)(v >> 16) - dlo;
        if ((unsigned)dl < 16u) {
            int pos = atomicAdd(&cur_s[dl], 1);
            if (pos < CAPP) srt[pos] = (unsigned short)(v & 0xFFFFu);
        }
    }
    __syncthreads();
    int wv = t >> 6, lane = t & 63;
    int q = lane >> 4, sl = lane & 15;
    #pragma unroll
    for (int i = 0; i < 4; ++i) {
        int dl = wv * 4 + i;
        int d = b * 64 + dlo + dl;
        if (d >= NN) continue;               // wave-uniform
        int start = base_s[dl], end = start + cnt_s[dl];
        float adv = aD[d];
        float2_t a = {0.f, 0.f};
        float den = 0.f;
        int j = start + q;
        for (; j + 4 < end; j += 8) {
            int s0 = srt[j], s1 = srt[j + 4];
            unsigned r0 = *(const unsigned*)&h2b[(size_t)s0 * HID + sl * 2];
            unsigned r1 = *(const unsigned*)&h2b[(size_t)s1 * HID + sl * 2];
            float e0 = __expf(lrelu(aS[s0] + adv));
            float e1 = __expf(lrelu(aS[s1] + adv));
            den += e0 + e1;
            a += (float2_t){e0, e0} * (float2_t){bf2f((unsigned short)(r0 & 0xffff)), bf2f((unsigned short)(r0 >> 16))};
            a += (float2_t){e1, e1} * (float2_t){bf2f((unsigned short)(r1 & 0xffff)), bf2f((unsigned short)(r1 >> 16))};
        }
        for (; j < end; j += 4) {
            int s = srt[j];
            unsigned r = *(const unsigned*)&h2b[(size_t)s * HID + sl * 2];
            float ee = __expf(lrelu(aS[s] + adv));
            den += ee;
            a += (float2_t){ee, ee} * (float2_t){bf2f((unsigned short)(r & 0xffff)), bf2f((unsigned short)(r >> 16))};
        }
        den += __shfl_xor(den, 16, 64);
        den += __shfl_xor(den, 32, 64);
        a.x += __shfl_xor(a.x, 16, 64); a.x += __shfl_xor(a.x, 32, 64);
        a.y += __shfl_xor(a.y, 16, 64); a.y += __shfl_xor(a.y, 32, 64);
        if (q == 0) {
            float invd = 1.f / (den + 1e-16f);
            float2 o;
            o.x = elu1(a.x * invd + b2[sl * 2]);
            o.y = elu1(a.y * invd + b2[sl * 2 + 1]);
            *(float2*)&z2[(size_t)d * HID + sl * 2] = o;
        }
    }
}

// ---------------- Pool: one block per group, contiguous slice, no atomics ----------------
__global__ __launch_bounds__(256) void pool_kernel(
        const float* __restrict__ z2, const int* __restrict__ batch,
        const float* __restrict__ Wo, const float* __restrict__ bo,
        float* __restrict__ out) {
    __shared__ float sm[256];
    int g = blockIdx.x;
    int t = threadIdx.x;
    int lo = 0, hi = NN;
    while (lo < hi) { int m = (lo + hi) >> 1; if (batch[m] < g) lo = m + 1; else hi = m; }
    int start = lo;
    hi = NN;
    while (lo < hi) { int m = (lo + hi) >> 1; if (batch[m] < g + 1) lo = m + 1; else hi = m; }
    int end = lo;
    int c = t & 31, r = t >> 5;
    float acc = 0.f;
    for (int n = start + r; n < end; n += 8)
        acc += z2[(size_t)n * HID + c];
    sm[t] = acc;
    __syncthreads();
    if (t < 32) {
        float s = 0.f;
        #pragma unroll
        for (int i = 0; i < 8; ++i) s += sm[t + 32 * i];
        float cntf = fmaxf((float)(end - start), 1.f);
        float part = (s / cntf) * Wo[t];
        #pragma unroll
        for (int off = 16; off; off >>= 1) part += __shfl_xor(part, off, 32);
        if (t == 0) out[g] = 1.f / (1.f + __expf(-(part + bo[0])));
    }
}

extern "C" void kernel_launch(void* const* d_in, const int* in_sizes, int n_in,
                              void* d_out, int out_size, void* d_ws, size_t ws_size,
                              hipStream_t stream) {
    const float* x     = (const float*)d_in[0];
    const int*   ei    = (const int*)d_in[1];
    const int*   batch = (const int*)d_in[2];
    const float* W1    = (const float*)d_in[3];
    const float* attS1 = (const float*)d_in[4];
    const float* attD1 = (const float*)d_in[5];
    const float* b1    = (const float*)d_in[6];
    const float* W2    = (const float*)d_in[7];
    const float* attS2 = (const float*)d_in[8];
    const float* attD2 = (const float*)d_in[9];
    const float* b2    = (const float*)d_in[10];
    const float* Wo    = (const float*)d_in[11];
    const float* bo    = (const float*)d_in[12];
    float* out = (float*)d_out;

    char* p = (char*)d_ws;
    auto alloc = [&](size_t bytes) {
        char* r = p;
        p += (bytes + 255) & ~(size_t)255;
        return (void*)r;
    };
    unsigned char*  h1f8  = (unsigned char*)alloc((size_t)NN * C1);
    unsigned short* w1swz = (unsigned short*)alloc((size_t)FIN * C1 * 2);
    unsigned short* w2swz = (unsigned short*)alloc((size_t)C1 * HID * 2);
    unsigned short* z1b   = (unsigned short*)alloc((size_t)NN * C1 * 2);
    unsigned short* h2b   = (unsigned short*)alloc((size_t)NN * HID * 2);
    float* aS1    = (float*)alloc((size_t)NN * HEADS * 4);
    float* aD1    = (float*)alloc((size_t)NN * HEADS * 4);
    float* z2     = (float*)alloc((size_t)NN * HID * 4);
    float* aS2    = (float*)alloc((size_t)NN * 4);
    float* aD2    = (float*)alloc((size_t)NN * 4);
    unsigned* bkt = (unsigned*)alloc((size_t)NBKT * CAP * 4);
    int*   bcur   = (int*)alloc((size_t)NBKT * 4);

    hipMemsetAsync(bcur, 0, (size_t)NBKT * 4, stream);
    cvt_w_kernel<<<20, 256, 0, stream>>>(W1, W2, w1swz, w2swz);
    bkt_scatter_kernel<<<(ET + EPB - 1) / EPB, 256, 0, stream>>>(ei, bcur, bkt);
    gemm1_kernel<<<(NN + 63) / 64, 256, 0, stream>>>(x, w1swz, attS1, attD1, h1f8, aS1, aD1);
    agg1_kernel<<<NBKT * 4, 256, 0, stream>>>(bkt, bcur, aS1, aD1, h1f8, b1, z1b);
    gemm2_kernel<<<(NN + 63) / 64, 256, 0, stream>>>(z1b, w2swz, attS2, attD2, h2b, aS2, aD2);
    agg2_kernel<<<NBKT * 4, 256, 0, stream>>>(bkt, bcur, aS2, aD2, h2b, b2, z2);
    pool_kernel<<<NG, 256, 0, stream>>>(z2, batch, Wo, bo, out);
}

// Round 13
// 244.047 us; speedup vs baseline: 1.0399x; 1.0399x over previous
//
#include <hip/hip_runtime.h>
#include <hip/hip_bf16.h>
#include <math.h>

#define NN 50000
#define NE 800000
#define ET (NE + NN)
#define FIN 128
#define HEADS 8
#define HID 32
#define C1 (HEADS * HID)   // 256
#define NG 64
#define NEG 0.2f

#define EPB 4096           // edges per block in bucket scatter
#define NBKT 782           // ceil(NN/64)
#define CAP 2048           // slots per bucket (expected ~1087)

typedef __attribute__((ext_vector_type(8))) unsigned short ushort8_t;
typedef __attribute__((ext_vector_type(4))) unsigned short ushort4_t;
typedef __attribute__((ext_vector_type(2))) float float2_t;
typedef __attribute__((ext_vector_type(8))) short bf16x8;
typedef __attribute__((ext_vector_type(4))) float f32x4;

__device__ __forceinline__ float lrelu(float v) { return v > 0.f ? v : NEG * v; }
__device__ __forceinline__ float elu1(float v)  { return v > 0.f ? v : expm1f(v); }
__device__ __forceinline__ unsigned short f2bf(float f) {
    __hip_bfloat16 b = __float2bfloat16(f);
    return *reinterpret_cast<unsigned short*>(&b);
}
__device__ __forceinline__ float bf2f(unsigned short u) {
    return __uint_as_float(((unsigned)u) << 16);
}
// decode 16 fp8 (uint4), accumulate e*val into 8 float2 accumulators (v_pk_fma_f32)
__device__ __forceinline__ void dec_fma16(uint4 r, float e, float2_t* acc) {
    float2_t ev = {e, e};
    acc[0] += ev * __builtin_amdgcn_cvt_pk_f32_fp8((int)r.x, false);
    acc[1] += ev * __builtin_amdgcn_cvt_pk_f32_fp8((int)r.x, true);
    acc[2] += ev * __builtin_amdgcn_cvt_pk_f32_fp8((int)r.y, false);
    acc[3] += ev * __builtin_amdgcn_cvt_pk_f32_fp8((int)r.y, true);
    acc[4] += ev * __builtin_amdgcn_cvt_pk_f32_fp8((int)r.z, false);
    acc[5] += ev * __builtin_amdgcn_cvt_pk_f32_fp8((int)r.z, true);
    acc[6] += ev * __builtin_amdgcn_cvt_pk_f32_fp8((int)r.w, false);
    acc[7] += ev * __builtin_amdgcn_cvt_pk_f32_fp8((int)r.w, true);
}

// ---------------- CSR build: two-level counting sort (packed uint entries) ----------------
// packed edge: s(16 bits) | (d&63)<<16 | (d>>6)<<22  — NN<65536, NBKT<1024
__global__ __launch_bounds__(256) void bkt_scatter_kernel(const int* __restrict__ ei,
                                                          int* __restrict__ bcur,
                                                          unsigned* __restrict__ bkt) {
    __shared__ unsigned ep[EPB];   // 16 KB
    __shared__ int lh[NBKT];       // 3.1 KB
    int t = threadIdx.x;
    int base = blockIdx.x * EPB;
    int nloc = ET - base; if (nloc > EPB) nloc = EPB;
    for (int i = t; i < NBKT; i += 256) lh[i] = 0;
    __syncthreads();
    for (int k = t; k < nloc; k += 256) {
        int i = base + k;
        int s, d;
        if (i < NE) { s = ei[i]; d = ei[NE + i]; }
        else        { s = i - NE; d = s; }
        ep[k] = (unsigned)s | ((unsigned)(d & 63) << 16) | ((unsigned)(d >> 6) << 22);
        atomicAdd(&lh[d >> 6], 1);
    }
    __syncthreads();
    for (int i = t; i < NBKT; i += 256) {
        int c = lh[i];
        lh[i] = c ? atomicAdd(&bcur[i], c) : 0;
    }
    __syncthreads();
    for (int k = t; k < nloc; k += 256) {
        unsigned v = ep[k];
        int b = (int)(v >> 22);
        int pos = atomicAdd(&lh[b], 1);
        if (pos < CAP) bkt[(size_t)b * CAP + pos] = v & 0x3FFFFFu;  // s | dl<<16
    }
}

__global__ __launch_bounds__(256) void bkt_scan_kernel(const int* __restrict__ bcur,
                                                       int* __restrict__ bbase,
                                                       int* __restrict__ rowptr) {
    __shared__ int wsum[4];
    int t = threadIdx.x, lane = t & 63, w = t >> 6;
    int idx = t * 4;
    int a0 = (idx + 0 < NBKT) ? bcur[idx + 0] : 0;
    int a1 = (idx + 1 < NBKT) ? bcur[idx + 1] : 0;
    int a2 = (idx + 2 < NBKT) ? bcur[idx + 2] : 0;
    int a3 = (idx + 3 < NBKT) ? bcur[idx + 3] : 0;
    int v = a0 + a1 + a2 + a3;
    int inc = v;
    #pragma unroll
    for (int off = 1; off < 64; off <<= 1) {
        int u = __shfl_up(inc, off, 64);
        if (lane >= off) inc += u;
    }
    if (lane == 63) wsum[w] = inc;
    __syncthreads();
    int woff = 0;
    #pragma unroll
    for (int i = 0; i < 4; ++i) if (i < w) woff += wsum[i];
    int excl = woff + inc - v;
    if (idx + 0 < NBKT) bbase[idx + 0] = excl;
    if (idx + 1 < NBKT) bbase[idx + 1] = excl + a0;
    if (idx + 2 < NBKT) bbase[idx + 2] = excl + a0 + a1;
    if (idx + 3 < NBKT) bbase[idx + 3] = excl + a0 + a1 + a2;
    if (t == 255) rowptr[NN] = woff + inc;   // = ET
}

__global__ __launch_bounds__(256) void csr_kernel(const unsigned* __restrict__ bkt,
                                                  const int* __restrict__ bcur,
                                                  const int* __restrict__ bbase,
                                                  int* __restrict__ rowptr,
                                                  int* __restrict__ ssrc) {
    __shared__ int nb[64];
    __shared__ int nc[64];
    int b = blockIdx.x, t = threadIdx.x;
    int cnt = bcur[b]; if (cnt > CAP) cnt = CAP;
    int gbase = bbase[b];
    if (t < 64) nc[t] = 0;
    __syncthreads();
    const unsigned* e = bkt + (size_t)b * CAP;
    for (int k = t; k < cnt; k += 256)
        atomicAdd(&nc[e[k] >> 16], 1);
    __syncthreads();
    if (t < 64) {
        int v = nc[t];
        int inc = v;
        #pragma unroll
        for (int off = 1; off < 64; off <<= 1) {
            int u = __shfl_up(inc, off, 64);
            if (t >= off) inc += u;
        }
        int start = gbase + inc - v;
        nb[t] = start;
        int node = b * 64 + t;
        if (node < NN) rowptr[node] = start;
    }
    __syncthreads();
    for (int k = t; k < cnt; k += 256) {
        unsigned v = e[k];
        int pos = atomicAdd(&nb[v >> 16], 1);
        ssrc[pos] = (int)(v & 0xFFFFu);
    }
}

// ---------------- W1 fp32 -> bf16 swizzled B-fragments ----------------
__global__ __launch_bounds__(256) void cvt_w1_kernel(const float* __restrict__ W1,
                                                     unsigned short* __restrict__ w1swz) {
    int t = blockIdx.x * 256 + threadIdx.x;
    int fid = t >> 6, lane = t & 63;
    int tnt = fid >> 2, ks = fid & 3;
    int n = tnt * 16 + (lane & 15);
    int k0 = ks * 32 + (lane >> 4) * 8;
    ushort8_t o;
    #pragma unroll
    for (int j = 0; j < 8; ++j) o[j] = f2bf(W1[(k0 + j) * C1 + n]);
    *(ushort8_t*)&w1swz[(size_t)(fid * 64 + lane) * 8] = o;
}

// ---------------- W2 fp32 -> bf16 swizzled B-fragments (nt 0..1, ks 0..7) ----------------
__global__ __launch_bounds__(256) void cvt_w2_kernel(const float* __restrict__ W2,
                                                     unsigned short* __restrict__ w2swz) {
    int t = blockIdx.x * 256 + threadIdx.x;   // 1024 threads
    int fid = t >> 6, lane = t & 63;          // fid 0..15
    int nt = fid >> 3, ks = fid & 7;
    int n = nt * 16 + (lane & 15);
    int k0 = ks * 32 + (lane >> 4) * 8;
    ushort8_t o;
    #pragma unroll
    for (int j = 0; j < 8; ++j) o[j] = f2bf(W2[(k0 + j) * HID + n]);
    *(ushort8_t*)&w2swz[(size_t)(fid * 64 + lane) * 8] = o;
}

// ---------------- GEMM1 (MFMA bf16, f32 x in): h1 = x @ W1 (fp8 out), fused att1 ----------------
__global__ __launch_bounds__(256) void gemm1_kernel(
        const float* __restrict__ x, const unsigned short* __restrict__ w1swz,
        const float* __restrict__ attS, const float* __restrict__ attD,
        unsigned char* __restrict__ h1f8, float* __restrict__ aS, float* __restrict__ aD) {
    __shared__ float lds[4 * 16 * 132];
    int t = threadIdx.x, w = t >> 6, lane = t & 63;
    int mh = w & 1, nh = w >> 1;
    int m0 = blockIdx.x * 64 + mh * 32;
    int l15 = lane & 15, l4 = lane >> 4;

    f32x4 acc[2][8];
    #pragma unroll
    for (int mt = 0; mt < 2; ++mt)
        #pragma unroll
        for (int nt = 0; nt < 8; ++nt)
            acc[mt][nt] = (f32x4){0.f, 0.f, 0.f, 0.f};

    int ra = m0 + l15;       if (ra >= NN) ra = NN - 1;
    int rb = m0 + 16 + l15;  if (rb >= NN) rb = NN - 1;
    const float* a0p = x + (size_t)ra * FIN + l4 * 8;
    const float* a1p = x + (size_t)rb * FIN + l4 * 8;

    #pragma unroll
    for (int ks = 0; ks < 4; ++ks) {
        float4 f00 = *(const float4*)(a0p + ks * 32);
        float4 f01 = *(const float4*)(a0p + ks * 32 + 4);
        float4 f10 = *(const float4*)(a1p + ks * 32);
        float4 f11 = *(const float4*)(a1p + ks * 32 + 4);
        bf16x8 af0, af1;
        af0[0] = (short)f2bf(f00.x); af0[1] = (short)f2bf(f00.y);
        af0[2] = (short)f2bf(f00.z); af0[3] = (short)f2bf(f00.w);
        af0[4] = (short)f2bf(f01.x); af0[5] = (short)f2bf(f01.y);
        af0[6] = (short)f2bf(f01.z); af0[7] = (short)f2bf(f01.w);
        af1[0] = (short)f2bf(f10.x); af1[1] = (short)f2bf(f10.y);
        af1[2] = (short)f2bf(f10.z); af1[3] = (short)f2bf(f10.w);
        af1[4] = (short)f2bf(f11.x); af1[5] = (short)f2bf(f11.y);
        af1[6] = (short)f2bf(f11.z); af1[7] = (short)f2bf(f11.w);
        #pragma unroll
        for (int nt = 0; nt < 8; ++nt) {
            bf16x8 bf = *(const bf16x8*)&w1swz[(size_t)(((nh * 8 + nt) * 4 + ks) * 64 + lane) * 8];
            acc[0][nt] = __builtin_amdgcn_mfma_f32_16x16x32_bf16(af0, bf, acc[0][nt], 0, 0, 0);
            acc[1][nt] = __builtin_amdgcn_mfma_f32_16x16x32_bf16(af1, bf, acc[1][nt], 0, 0, 0);
        }
    }

    float* wl = lds + w * 16 * 132;
    #pragma unroll
    for (int mt = 0; mt < 2; ++mt) {
        __syncthreads();
        #pragma unroll
        for (int nt = 0; nt < 8; ++nt)
            #pragma unroll
            for (int r = 0; r < 4; ++r)
                wl[(l4 * 4 + r) * 132 + nt * 16 + l15] = acc[mt][nt][r];
        __syncthreads();
        int row_g = m0 + mt * 16 + l15;
        int cch = l4;
        float v[32];
        #pragma unroll
        for (int i = 0; i < 8; ++i) {
            float4 f = *(const float4*)&wl[l15 * 132 + cch * 32 + i * 4];
            v[i * 4 + 0] = f.x; v[i * 4 + 1] = f.y; v[i * 4 + 2] = f.z; v[i * 4 + 3] = f.w;
        }
        if (row_g < NN) {
            unsigned pk[8];
            #pragma unroll
            for (int i = 0; i < 8; ++i) {
                int p = __builtin_amdgcn_cvt_pk_fp8_f32(v[i * 4 + 0], v[i * 4 + 1], 0, false);
                p = __builtin_amdgcn_cvt_pk_fp8_f32(v[i * 4 + 2], v[i * 4 + 3], p, true);
                pk[i] = (unsigned)p;
            }
            size_t base = (size_t)row_g * C1 + nh * 128 + cch * 32;
            *(uint4*)&h1f8[base]      = make_uint4(pk[0], pk[1], pk[2], pk[3]);
            *(uint4*)&h1f8[base + 16] = make_uint4(pk[4], pk[5], pk[6], pk[7]);
            int h = nh * 4 + cch;
            float ps = 0.f, pd = 0.f;
            #pragma unroll
            for (int i = 0; i < 32; ++i) {
                ps += v[i] * attS[h * 32 + i];
                pd += v[i] * attD[h * 32 + i];
            }
            aS[row_g * HEADS + h] = ps;
            aD[row_g * HEADS + h] = pd;
        }
    }
}

// ---------------- Layer-1 aggregation: quarter-wave per edge, pk_fma accumulate ----------------
__global__ __launch_bounds__(256) void agg1_kernel(
        const int* __restrict__ rowptr, const int* __restrict__ ssrc,
        const float* __restrict__ aS, const float* __restrict__ aD,
        const unsigned char* __restrict__ h1f8, const float* __restrict__ b1,
        unsigned short* __restrict__ z1b) {
    int d = (blockIdx.x * 256 + threadIdx.x) >> 6;
    int lane = threadIdx.x & 63;
    if (d >= NN) return;
    int start = rowptr[d], end = rowptr[d + 1];
    int q = lane >> 4, sl = lane & 15;
    int h = sl >> 1;
    float adh = aD[d * HEADS + h];
    float2_t acc[8];
    #pragma unroll
    for (int i = 0; i < 8; ++i) acc[i] = (float2_t){0.f, 0.f};
    float den = 0.f;
    int j = start + q;
    for (; j + 4 < end; j += 8) {
        int s0 = ssrc[j], s1 = ssrc[j + 4];
        uint4 r0 = *(const uint4*)&h1f8[(size_t)s0 * C1 + sl * 16];
        uint4 r1 = *(const uint4*)&h1f8[(size_t)s1 * C1 + sl * 16];
        float e0 = __expf(lrelu(aS[s0 * HEADS + h] + adh));
        float e1 = __expf(lrelu(aS[s1 * HEADS + h] + adh));
        den += e0 + e1;
        dec_fma16(r0, e0, acc);
        dec_fma16(r1, e1, acc);
    }
    for (; j < end; j += 4) {
        int s = ssrc[j];
        uint4 r = *(const uint4*)&h1f8[(size_t)s * C1 + sl * 16];
        float e = __expf(lrelu(aS[s * HEADS + h] + adh));
        den += e;
        dec_fma16(r, e, acc);
    }
    den += __shfl_xor(den, 16, 64);
    den += __shfl_xor(den, 32, 64);
    #pragma unroll
    for (int i = 0; i < 8; ++i) {
        acc[i].x += __shfl_xor(acc[i].x, 16, 64);
        acc[i].y += __shfl_xor(acc[i].y, 16, 64);
        acc[i].x += __shfl_xor(acc[i].x, 32, 64);
        acc[i].y += __shfl_xor(acc[i].y, 32, 64);
    }
    float invd = 1.f / (den + 1e-16f);
    int cb = sl * 16 + q * 4;
    float4 bb = *(const float4*)&b1[cb];
    ushort4_t o;
    o[0] = f2bf(elu1(acc[q * 2 + 0].x * invd + bb.x));
    o[1] = f2bf(elu1(acc[q * 2 + 0].y * invd + bb.y));
    o[2] = f2bf(elu1(acc[q * 2 + 1].x * invd + bb.z));
    o[3] = f2bf(elu1(acc[q * 2 + 1].y * invd + bb.w));
    *(ushort4_t*)&z1b[(size_t)d * C1 + cb] = o;
}

// ---------------- GEMM2 (MFMA bf16): h2 = z1 @ W2 (bf16 out), fused att2 ----------------
__global__ __launch_bounds__(256) void gemm2_kernel(
        const unsigned short* __restrict__ z1b, const unsigned short* __restrict__ w2swz,
        const float* __restrict__ attS, const float* __restrict__ attD,
        unsigned short* __restrict__ h2b, float* __restrict__ aS2, float* __restrict__ aD2) {
    __shared__ float lds[4 * 16 * 36];
    int t = threadIdx.x, w = t >> 6, lane = t & 63;
    int m0 = blockIdx.x * 64 + w * 16;
    int l15 = lane & 15, l4 = lane >> 4;

    f32x4 acc[2];
    acc[0] = (f32x4){0.f, 0.f, 0.f, 0.f};
    acc[1] = (f32x4){0.f, 0.f, 0.f, 0.f};

    int ra = m0 + l15; if (ra >= NN) ra = NN - 1;
    const unsigned short* ap = z1b + (size_t)ra * C1 + l4 * 8;

    #pragma unroll
    for (int ks = 0; ks < 8; ++ks) {
        bf16x8 af = *(const bf16x8*)(ap + ks * 32);
        #pragma unroll
        for (int nt = 0; nt < 2; ++nt) {
            bf16x8 bf = *(const bf16x8*)&w2swz[(size_t)((nt * 8 + ks) * 64 + lane) * 8];
            acc[nt] = __builtin_amdgcn_mfma_f32_16x16x32_bf16(af, bf, acc[nt], 0, 0, 0);
        }
    }
    float* wl = lds + w * 16 * 36;
    #pragma unroll
    for (int nt = 0; nt < 2; ++nt)
        #pragma unroll
        for (int r = 0; r < 4; ++r)
            wl[(l4 * 4 + r) * 36 + nt * 16 + l15] = acc[nt][r];
    __syncthreads();
    int row_g = m0 + l15;
    float v[8];
    {
        float4 f0 = *(const float4*)&wl[l15 * 36 + l4 * 8];
        float4 f1 = *(const float4*)&wl[l15 * 36 + l4 * 8 + 4];
        v[0] = f0.x; v[1] = f0.y; v[2] = f0.z; v[3] = f0.w;
        v[4] = f1.x; v[5] = f1.y; v[6] = f1.z; v[7] = f1.w;
    }
    float ps = 0.f, pd = 0.f;
    #pragma unroll
    for (int i = 0; i < 8; ++i) {
        ps += v[i] * attS[l4 * 8 + i];
        pd += v[i] * attD[l4 * 8 + i];
    }
    ps += __shfl_xor(ps, 16, 64); ps += __shfl_xor(ps, 32, 64);
    pd += __shfl_xor(pd, 16, 64); pd += __shfl_xor(pd, 32, 64);
    if (row_g < NN) {
        ushort8_t o;
        #pragma unroll
        for (int i = 0; i < 8; ++i) o[i] = f2bf(v[i]);
        *(ushort8_t*)&h2b[(size_t)row_g * HID + l4 * 8] = o;
        if (l4 == 0) { aS2[row_g] = ps; aD2[row_g] = pd; }
    }
}

// ---------------- Layer-2 aggregation: quarter-wave per edge ----------------
__global__ __launch_bounds__(256) void agg2_kernel(
        const int* __restrict__ rowptr, const int* __restrict__ ssrc,
        const float* __restrict__ aS, const float* __restrict__ aD,
        const unsigned short* __restrict__ h2b, const float* __restrict__ b2,
        float* __restrict__ z2) {
    int d = (blockIdx.x * 256 + threadIdx.x) >> 6;
    int lane = threadIdx.x & 63;
    if (d >= NN) return;
    int start = rowptr[d], end = rowptr[d + 1];
    int q = lane >> 4, sl = lane & 15;
    float adv = aD[d];
    float2_t a = {0.f, 0.f};
    float den = 0.f;
    int j = start + q;
    for (; j + 4 < end; j += 8) {
        int s0 = ssrc[j], s1 = ssrc[j + 4];
        unsigned r0 = *(const unsigned*)&h2b[(size_t)s0 * HID + sl * 2];
        unsigned r1 = *(const unsigned*)&h2b[(size_t)s1 * HID + sl * 2];
        float e0 = __expf(lrelu(aS[s0] + adv));
        float e1 = __expf(lrelu(aS[s1] + adv));
        den += e0 + e1;
        float2_t v0 = {bf2f((unsigned short)(r0 & 0xffff)), bf2f((unsigned short)(r0 >> 16))};
        float2_t v1 = {bf2f((unsigned short)(r1 & 0xffff)), bf2f((unsigned short)(r1 >> 16))};
        a += (float2_t){e0, e0} * v0;
        a += (float2_t){e1, e1} * v1;
    }
    for (; j < end; j += 4) {
        int s = ssrc[j];
        unsigned r = *(const unsigned*)&h2b[(size_t)s * HID + sl * 2];
        float e = __expf(lrelu(aS[s] + adv));
        den += e;
        float2_t v = {bf2f((unsigned short)(r & 0xffff)), bf2f((unsigned short)(r >> 16))};
        a += (float2_t){e, e} * v;
    }
    den += __shfl_xor(den, 16, 64);
    den += __shfl_xor(den, 32, 64);
    a.x += __shfl_xor(a.x, 16, 64); a.x += __shfl_xor(a.x, 32, 64);
    a.y += __shfl_xor(a.y, 16, 64); a.y += __shfl_xor(a.y, 32, 64);
    if (q == 0) {
        float invd = 1.f / (den + 1e-16f);
        float2 o;
        o.x = elu1(a.x * invd + b2[sl * 2]);
        o.y = elu1(a.y * invd + b2[sl * 2 + 1]);
        *(float2*)&z2[(size_t)d * HID + sl * 2] = o;
    }
}

// ---------------- Pool partial: 16 blocks per group, LDS reduce + few atomics ----------------
__global__ __launch_bounds__(256) void pool_partial_kernel(
        const float* __restrict__ z2, const int* __restrict__ batch,
        float* __restrict__ pooled) {
    __shared__ float sm[256];
    int g = blockIdx.x >> 4, slice = blockIdx.x & 15;
    int t = threadIdx.x;
    int lo = 0, hi = NN;
    while (lo < hi) { int m = (lo + hi) >> 1; if (batch[m] < g) lo = m + 1; else hi = m; }
    int start = lo;
    hi = NN;
    while (lo < hi) { int m = (lo + hi) >> 1; if (batch[m] < g + 1) lo = m + 1; else hi = m; }
    int end = lo;
    int len = end - start;
    int s0 = start + (int)(((long long)len * slice) >> 4);
    int s1 = start + (int)(((long long)len * (slice + 1)) >> 4);
    int c = t & 31, r = t >> 5;
    float acc = 0.f;
    for (int n = s0 + r; n < s1; n += 8)
        acc += z2[(size_t)n * HID + c];
    sm[t] = acc;
    __syncthreads();
    if (t < 32) {
        float s = 0.f;
        #pragma unroll
        for (int i = 0; i < 8; ++i) s += sm[t + 32 * i];
        atomicAdd(&pooled[g * HID + t], s);
    }
}

// ---------------- Finish: mean + Wo + sigmoid ----------------
__global__ void pool_finish_kernel(const float* __restrict__ pooled,
                                   const int* __restrict__ batch,
                                   const float* __restrict__ Wo, const float* __restrict__ bo,
                                   float* __restrict__ out) {
    int g = threadIdx.x;
    if (g >= NG) return;
    int lo = 0, hi = NN;
    while (lo < hi) { int m = (lo + hi) >> 1; if (batch[m] < g) lo = m + 1; else hi = m; }
    int start = lo;
    hi = NN;
    while (lo < hi) { int m = (lo + hi) >> 1; if (batch[m] < g + 1) lo = m + 1; else hi = m; }
    int end = lo;
    float c = fmaxf((float)(end - start), 1.f);
    float acc = 0.f;
    for (int i = 0; i < HID; ++i) acc += (pooled[g * HID + i] / c) * Wo[i];
    acc += bo[0];
    out[g] = 1.f / (1.f + __expf(-acc));
}

extern "C" void kernel_launch(void* const* d_in, const int* in_sizes, int n_in,
                              void* d_out, int out_size, void* d_ws, size_t ws_size,
                              hipStream_t stream) {
    const float* x     = (const float*)d_in[0];
    const int*   ei    = (const int*)d_in[1];
    const int*   batch = (const int*)d_in[2];
    const float* W1    = (const float*)d_in[3];
    const float* attS1 = (const float*)d_in[4];
    const float* attD1 = (const float*)d_in[5];
    const float* b1    = (const float*)d_in[6];
    const float* W2    = (const float*)d_in[7];
    const float* attS2 = (const float*)d_in[8];
    const float* attD2 = (const float*)d_in[9];
    const float* b2    = (const float*)d_in[10];
    const float* Wo    = (const float*)d_in[11];
    const float* bo    = (const float*)d_in[12];
    float* out = (float*)d_out;

    char* p = (char*)d_ws;
    auto alloc = [&](size_t bytes) {
        char* r = p;
        p += (bytes + 255) & ~(size_t)255;
        return (void*)r;
    };
    unsigned char*  h1f8  = (unsigned char*)alloc((size_t)NN * C1);
    unsigned short* w1swz = (unsigned short*)alloc((size_t)FIN * C1 * 2);
    unsigned short* w2swz = (unsigned short*)alloc((size_t)C1 * HID * 2);
    unsigned short* z1b   = (unsigned short*)alloc((size_t)NN * C1 * 2);
    unsigned short* h2b   = (unsigned short*)alloc((size_t)NN * HID * 2);
    float* aS1    = (float*)alloc((size_t)NN * HEADS * 4);
    float* aD1    = (float*)alloc((size_t)NN * HEADS * 4);
    float* z2     = (float*)alloc((size_t)NN * HID * 4);
    float* aS2    = (float*)alloc((size_t)NN * 4);
    float* aD2    = (float*)alloc((size_t)NN * 4);
    int*   rowptr = (int*)alloc((size_t)(NN + 1) * 4);
    int*   ssrc   = (int*)alloc((size_t)ET * 4);
    unsigned* bkt = (unsigned*)alloc((size_t)NBKT * CAP * 4);
    int*   bbase  = (int*)alloc((size_t)NBKT * 4);
    // zero-init region: bcur + pooled (contiguous)
    int*   bcur   = (int*)alloc((size_t)NBKT * 4);
    float* pooled = (float*)alloc((size_t)NG * HID * 4);
    size_t zero_bytes = (size_t)(p - (char*)bcur);

    hipMemsetAsync(bcur, 0, zero_bytes, stream);
    bkt_scatter_kernel<<<(ET + EPB - 1) / EPB, 256, 0, stream>>>(ei, bcur, bkt);
    bkt_scan_kernel<<<1, 256, 0, stream>>>(bcur, bbase, rowptr);
    csr_kernel<<<NBKT, 256, 0, stream>>>(bkt, bcur, bbase, rowptr, ssrc);
    cvt_w1_kernel<<<16, 256, 0, stream>>>(W1, w1swz);
    cvt_w2_kernel<<<4, 256, 0, stream>>>(W2, w2swz);
    gemm1_kernel<<<(NN + 63) / 64, 256, 0, stream>>>(x, w1swz, attS1, attD1, h1f8, aS1, aD1);
    agg1_kernel<<<(NN * 64) / 256, 256, 0, stream>>>(rowptr, ssrc, aS1, aD1, h1f8, b1, z1b);
    gemm2_kernel<<<(NN + 63) / 64, 256, 0, stream>>>(z1b, w2swz, attS2, attD2, h2b, aS2, aD2);
    agg2_kernel<<<(NN * 64 + 255) / 256, 256, 0, stream>>>(rowptr, ssrc, aS2, aD2, h2b, b2, z2);
    pool_partial_kernel<<<NG * 16, 256, 0, stream>>>(z2, batch, pooled);
    pool_finish_kernel<<<1, 64, 0, stream>>>(pooled, batch, Wo, bo, out);
}